// Round 7
// baseline (185.541 us; speedup 1.0000x reference)
//
#include <hip/hip_runtime.h>

typedef unsigned short ushort_t;
typedef short s16x8 __attribute__((ext_vector_type(8)));   // bf16 frag vector
typedef float f32x4 __attribute__((ext_vector_type(4)));

#define DEVINL __device__ __forceinline__

DEVINL ushort_t f2b(float f) {           // fp32 -> bf16 RNE
  union { float f; unsigned int u; } v; v.f = f;
  unsigned int r = (v.u + 0x7fffu + ((v.u >> 16) & 1u)) >> 16;
  return (ushort_t)r;
}

// ------------- transpose+convert: out_bf16[n*K+k] = in_f32[k*N+n] -------------
__global__ __launch_bounds__(256) void transpose_conv_kernel(
    const float* __restrict__ in, ushort_t* __restrict__ out, int K, int N)
{
  __shared__ ushort_t tile[64 * 72];
  const int tid = threadIdx.x;
  const int n0 = blockIdx.x * 64, k0 = blockIdx.y * 64;
  const int cr = tid >> 4;          // 0..15
  const int cc = (tid & 15) * 4;    // 0..60
#pragma unroll
  for (int p = 0; p < 4; p++) {
    int k = k0 + p * 16 + cr;
    float4 v = *(const float4*)(in + k * N + n0 + cc);
    ushort4 o; o.x = f2b(v.x); o.y = f2b(v.y); o.z = f2b(v.z); o.w = f2b(v.w);
    *(ushort4*)(tile + (p * 16 + cr) * 72 + cc) = o;
  }
  __syncthreads();
#pragma unroll
  for (int p = 0; p < 4; p++) {
    int n = n0 + p * 16 + cr;
    ushort4 v;
    v.x = tile[(cc + 0) * 72 + p * 16 + cr];
    v.y = tile[(cc + 1) * 72 + p * 16 + cr];
    v.z = tile[(cc + 2) * 72 + p * 16 + cr];
    v.w = tile[(cc + 3) * 72 + p * 16 + cr];
    *(ushort4*)(out + n * K + k0 + cc) = v;
  }
}

// ------------- fold: Wcomb (512x16) fp32, bcomb (16) fp32 -------------
__global__ __launch_bounds__(64) void fold_kernel(
    const float* __restrict__ Wq, const float* __restrict__ bq,
    const float* __restrict__ Wod, const float* __restrict__ bod,
    float* __restrict__ Wcomb, float* __restrict__ bcomb)
{
  const int c = blockIdx.x, lane = threadIdx.x;
  float a[8];
  const float* src = (c < 512) ? (Wq + c * 1536 + lane * 8) : (bq + lane * 8);
  float4 a0 = *(const float4*)(src);
  float4 a1 = *(const float4*)(src + 4);
  a[0]=a0.x; a[1]=a0.y; a[2]=a0.z; a[3]=a0.w;
  a[4]=a1.x; a[5]=a1.y; a[6]=a1.z; a[7]=a1.w;

  float s[16];
#pragma unroll
  for (int j = 0; j < 16; j++) s[j] = 0.f;
#pragma unroll
  for (int i = 0; i < 8; i++) {
    const float* wp = Wod + (lane * 8 + i) * 16;
#pragma unroll
    for (int j = 0; j < 16; j++) s[j] += a[i] * wp[j];
  }
#pragma unroll
  for (int mask = 1; mask < 64; mask <<= 1)
#pragma unroll
    for (int j = 0; j < 16; j++) s[j] += __shfl_xor(s[j], mask);

  if (lane < 16) {
    if (c < 512) Wcomb[c * 16 + lane] = s[lane];
    else         bcomb[lane] = s[lane] + bod[lane];
  }
}

// ---------------- od (fp32) + x->bf16 conversion fused ----------------
__global__ __launch_bounds__(256) void od_kernel(
    const float* __restrict__ x, const float* __restrict__ Wcomb,
    const float* __restrict__ bcomb, const int* __restrict__ lenp,
    float* __restrict__ params, ushort_t* __restrict__ xb)
{
  const int w = threadIdx.x >> 6, lane = threadIdx.x & 63;
  const int m = blockIdx.x * 4 + w;   // 0..2047
  int li = lenp[0];
  float len = (li > 0 && li < 1048576) ? (float)li : 1024.0f;

  const float* qp = x + m * 512 + lane * 8;
  float q[8];
  float4 qa = *(const float4*)(qp);
  float4 qb = *(const float4*)(qp + 4);
  q[0]=qa.x; q[1]=qa.y; q[2]=qa.z; q[3]=qa.w;
  q[4]=qb.x; q[5]=qb.y; q[6]=qb.z; q[7]=qb.w;

  s16x8 ov;
#pragma unroll
  for (int i = 0; i < 8; i++) ov[i] = (short)f2b(q[i]);
  *(s16x8*)(xb + m * 512 + lane * 8) = ov;

  float s[16];
#pragma unroll
  for (int j = 0; j < 16; j++) s[j] = 0.f;
#pragma unroll
  for (int i = 0; i < 8; i++) {
    const float* wp = Wcomb + (lane * 8 + i) * 16;
#pragma unroll
    for (int j = 0; j < 16; j++) s[j] += q[i] * wp[j];
  }
#pragma unroll
  for (int mask = 1; mask < 64; mask <<= 1)
#pragma unroll
    for (int j = 0; j < 16; j++) s[j] += __shfl_xor(s[j], mask);

  if (lane < 8) {
    int h = lane;
    int bb = m >> 10, t = m & 1023;
    float odo = s[h] + bcomb[h];
    float odd = s[8 + h] + bcomb[8 + h];
    float offset = tanhf(odo) * len;
    float dur = len / (1.f + expf(-odd));
    float anchor = (float)t + offset;
    float start = anchor - dur, end = anchor + dur;
    float bl = floorf(start), br = ceilf(end);
    float al = floorf(anchor);
    float da = anchor - al;
    float* pp = params + ((bb * 8 + h) * 1024 + t) * 6;
    pp[0] = bl; pp[1] = br; pp[2] = al;
    pp[3] = bl - start; pp[4] = end - br; pp[5] = da;
  }
}

// ------- qkv GEMM: 64x128 tiles, grid (12,32)=384 blocks for CU coverage -------
// Q pre-scaled by 0.125; V written row-major (coalesced), transposed separately.
__global__ __launch_bounds__(256) void qkv_gemm_kernel(
    const ushort_t* __restrict__ xb, const ushort_t* __restrict__ WT,
    const float* __restrict__ bqkv,
    ushort_t* __restrict__ Qh, ushort_t* __restrict__ Kh, ushort_t* __restrict__ Vh)
{
  __shared__ ushort_t As[64 * 32];
  __shared__ ushort_t Bs[128 * 32];
  const int tid = threadIdx.x;
  const int lane = tid & 63, w = tid >> 6;
  const int wr = w >> 1, wc = w & 1;          // wave tile 32x64
  const int quad = lane >> 4, l16 = lane & 15;
  const int m0 = blockIdx.y * 64, n0 = blockIdx.x * 128;

  f32x4 acc[2][4];
#pragma unroll
  for (int i = 0; i < 2; i++)
#pragma unroll
    for (int j = 0; j < 4; j++) acc[i][j] = f32x4{0.f, 0.f, 0.f, 0.f};

  const int idx = tid * 8;
  const int ra = idx >> 5, ca = idx & 31;
  const int rb1 = (idx + 2048) >> 5, cb1 = (idx + 2048) & 31;

  for (int k0 = 0; k0 < 512; k0 += 32) {
    s16x8 va  = *(const s16x8*)(xb + (m0 + ra) * 512 + k0 + ca);
    s16x8 vb0 = *(const s16x8*)(WT + (n0 + ra) * 512 + k0 + ca);
    s16x8 vb1 = *(const s16x8*)(WT + (n0 + rb1) * 512 + k0 + cb1);
    __syncthreads();
    *(s16x8*)(As + idx) = va;
    *(s16x8*)(Bs + idx) = vb0;
    *(s16x8*)(Bs + idx + 2048) = vb1;
    __syncthreads();

    s16x8 af[2], bfr[4];
#pragma unroll
    for (int mt = 0; mt < 2; mt++)
      af[mt] = *(const s16x8*)(As + (wr * 32 + mt * 16 + l16) * 32 + quad * 8);
#pragma unroll
    for (int nt = 0; nt < 4; nt++)
      bfr[nt] = *(const s16x8*)(Bs + (wc * 64 + nt * 16 + l16) * 32 + quad * 8);
#pragma unroll
    for (int mt = 0; mt < 2; mt++)
#pragma unroll
      for (int nt = 0; nt < 4; nt++)
        acc[mt][nt] = __builtin_amdgcn_mfma_f32_16x16x32_bf16(af[mt], bfr[nt], acc[mt][nt], 0, 0, 0);
  }

#pragma unroll
  for (int nt = 0; nt < 4; nt++) {
    int c = n0 + wc * 64 + nt * 16 + l16;
    float bias = bqkv[c];
    int which = c >> 9;
    int e = c & 511;
    int h = e >> 6, d = e & 63;
#pragma unroll
    for (int mt = 0; mt < 2; mt++) {
#pragma unroll
      for (int rr = 0; rr < 4; rr++) {
        int m = m0 + wr * 32 + mt * 16 + quad * 4 + rr;
        float v = acc[mt][nt][rr] + bias;
        int bb = m >> 10, t = m & 1023;
        int bh = bb * 8 + h;
        if (which == 0)      Qh[(bh * 1024 + t) * 64 + d] = f2b(v * 0.125f);
        else if (which == 1) Kh[(bh * 1024 + t) * 64 + d] = f2b(v);
        else                 Vh[(bh * 1024 + t) * 64 + d] = f2b(v);
      }
    }
  }
}

// ------------- V transpose: VT[bh][d][t] = Vh[bh][t][d] -------------
__global__ __launch_bounds__(256) void v_transpose_kernel(
    const ushort_t* __restrict__ in, ushort_t* __restrict__ out)
{
  __shared__ ushort_t tile[64 * 72];
  const int tid = threadIdx.x;
  const int bh = blockIdx.y, t0 = blockIdx.x * 64;
  const int cr = tid >> 4;
  const int cc = (tid & 15) * 4;
#pragma unroll
  for (int p = 0; p < 4; p++) {
    int t = t0 + p * 16 + cr;
    ushort4 v = *(const ushort4*)(in + (bh * 1024 + t) * 64 + cc);
    *(ushort4*)(tile + (p * 16 + cr) * 72 + cc) = v;
  }
  __syncthreads();
#pragma unroll
  for (int p = 0; p < 4; p++) {
    int d = p * 16 + cr;
    ushort4 v;
    v.x = tile[(cc + 0) * 72 + d];
    v.y = tile[(cc + 1) * 72 + d];
    v.z = tile[(cc + 2) * 72 + d];
    v.w = tile[(cc + 3) * 72 + d];
    *(ushort4*)(out + (bh * 64 + d) * 1024 + t0 + cc) = v;
  }
}

// ------- attention: no-max softmax, split-8 (512 threads), atomic LDS merge -------
// grid (bh, qtile): all blocks of a head land on one XCD (i%8 heuristic).
__global__ __launch_bounds__(512) void attn_kernel(
    const ushort_t* __restrict__ Qh, const ushort_t* __restrict__ Kh,
    const ushort_t* __restrict__ VT, const float* __restrict__ params,
    ushort_t* __restrict__ Oh)
{
  __shared__ ushort_t Plds[8 * 16 * 72];   // 18.4 KB, wave-private slabs
  __shared__ float Om[16 * 65];            // 4.2 KB merged O accumulator
  __shared__ float lwS[16];                // merged row sums

  const int tid = threadIdx.x;
  const int lane = tid & 63, w = tid >> 6;  // w in 0..7
  const int quad = lane >> 4, l16 = lane & 15;
  const int bh = blockIdx.x;
  const int mrow = blockIdx.y * 16;
  ushort_t* Pw = Plds + w * (16 * 72);

  for (int i = tid; i < 16 * 65; i += 512) Om[i] = 0.f;
  if (tid < 16) lwS[tid] = 0.f;
  __syncthreads();

  s16x8 aq0 = *(const s16x8*)(Qh + (bh * 1024 + mrow + l16) * 64 + quad * 8);
  s16x8 aq1 = *(const s16x8*)(Qh + (bh * 1024 + mrow + l16) * 64 + 32 + quad * 8);

  float bl[4], br[4], al[4], wl[4], wr2[4], da[4];
  float lo = 1.0e9f, hi = -1.0e9f;
#pragma unroll
  for (int rr = 0; rr < 4; rr++) {
    int row = mrow + quad * 4 + rr;
    const float* pp = params + (bh * 1024 + row) * 6;
    bl[rr] = pp[0]; br[rr] = pp[1]; al[rr] = pp[2];
    wl[rr] = pp[3]; wr2[rr] = pp[4]; da[rr] = pp[5];
    bool empty = (br[rr] < 0.f) || (bl[rr] > 1023.f);
    float lo_r = empty ? 0.f    : fmaxf(bl[rr], 0.f);
    float hi_r = empty ? 1023.f : fminf(br[rr], 1023.f);
    lo = fminf(lo, lo_r); hi = fmaxf(hi, hi_r);
  }
  lo = fminf(lo, __shfl_xor(lo, 16));
  lo = fminf(lo, __shfl_xor(lo, 32));
  hi = fmaxf(hi, __shfl_xor(hi, 16));
  hi = fmaxf(hi, __shfl_xor(hi, 32));
  const int tlo = ((int)lo) >> 6, thi = ((int)hi) >> 6;

  float lr[4] = {0.f, 0.f, 0.f, 0.f};
  f32x4 Oacc[4];
#pragma unroll
  for (int nt = 0; nt < 4; nt++) Oacc[nt] = f32x4{0.f, 0.f, 0.f, 0.f};

  // interleaved tile ownership: wave w takes tlo+w, tlo+w+8, ...
  for (int tt = tlo + w; tt <= thi; tt += 8) {
    const int r0 = tt * 64;
    f32x4 S[4];
#pragma unroll
    for (int nt = 0; nt < 4; nt++) {
      const ushort_t* kp = Kh + (bh * 1024 + r0 + nt * 16 + l16) * 64 + quad * 8;
      s16x8 bk0 = *(const s16x8*)(kp);
      s16x8 bk1 = *(const s16x8*)(kp + 32);
      f32x4 z = {0.f, 0.f, 0.f, 0.f};
      z = __builtin_amdgcn_mfma_f32_16x16x32_bf16(aq0, bk0, z, 0, 0, 0);
      z = __builtin_amdgcn_mfma_f32_16x16x32_bf16(aq1, bk1, z, 0, 0, 0);
      S[nt] = z;
    }

    // point-weight + mask + exp (no max subtraction: |s*wgt| <= ~12, fp32-safe;
    // mask=-30 => exp ~ 9e-14; all-masked row degrades to uniform softmax,
    // matching the reference's softmax over constant -1e8)
#pragma unroll
    for (int nt = 0; nt < 4; nt++) {
      float cf = (float)(r0 + nt * 16 + l16);
#pragma unroll
      for (int rr = 0; rr < 4; rr++) {
        float s = S[nt][rr];   // already includes 0.125 via Qh pre-scale
        float wgt = 1.f;
        wgt += (cf == bl[rr]) ? wl[rr] : 0.f;
        wgt += (cf == br[rr]) ? wr2[rr] : 0.f;
        wgt += (cf == al[rr] + 1.f) ? da[rr] : 0.f;
        wgt += (cf == al[rr]) ? (1.f - da[rr]) : 0.f;
        s *= wgt;
        s = (cf < bl[rr] || cf > br[rr]) ? -30.f : s;
        float p = __expf(s);
        lr[rr] += p;
        S[nt][rr] = p;
      }
    }

    // P (C-layout) -> wave-private LDS -> A-operand layout
#pragma unroll
    for (int nt = 0; nt < 4; nt++)
#pragma unroll
      for (int rr = 0; rr < 4; rr++)
        Pw[(quad * 4 + rr) * 72 + nt * 16 + l16] = f2b(S[nt][rr]);

    __asm__ volatile("s_waitcnt lgkmcnt(0)" ::: "memory");

    s16x8 pa0 = *(const s16x8*)(Pw + l16 * 72 + quad * 8);
    s16x8 pa1 = *(const s16x8*)(Pw + l16 * 72 + 32 + quad * 8);

#pragma unroll
    for (int nt = 0; nt < 4; nt++) {
      const ushort_t* vp = VT + (bh * 64 + nt * 16 + l16) * 1024 + r0 + quad * 8;
      s16x8 bv0 = *(const s16x8*)(vp);
      s16x8 bv1 = *(const s16x8*)(vp + 32);
      Oacc[nt] = __builtin_amdgcn_mfma_f32_16x16x32_bf16(pa0, bv0, Oacc[nt], 0, 0, 0);
      Oacc[nt] = __builtin_amdgcn_mfma_f32_16x16x32_bf16(pa1, bv1, Oacc[nt], 0, 0, 0);
    }
  }

  // one row-sum reduction after the loop, then atomic merge into shared state
#pragma unroll
  for (int mask = 1; mask < 16; mask <<= 1)
#pragma unroll
    for (int rr = 0; rr < 4; rr++) lr[rr] += __shfl_xor(lr[rr], mask);

#pragma unroll
  for (int nt = 0; nt < 4; nt++)
#pragma unroll
    for (int rr = 0; rr < 4; rr++)
      atomicAdd(&Om[(quad * 4 + rr) * 65 + nt * 16 + l16], Oacc[nt][rr]);
  if (l16 == 0) {
#pragma unroll
    for (int rr = 0; rr < 4; rr++) atomicAdd(&lwS[quad * 4 + rr], lr[rr]);
  }
  __syncthreads();

  const int bb = bh >> 3, h = bh & 7;
  for (int e = tid; e < 1024; e += 512) {
    int r = e >> 6, col = e & 63;
    int t = mrow + r;
    Oh[((bb << 10) + t) * 512 + h * 64 + col] = f2b(Om[r * 65 + col] / lwS[r]);
  }
}

// ------- out GEMM: 64x64 tiles, grid (8,32)=256 blocks for CU coverage -------
__global__ __launch_bounds__(256) void out_gemm_kernel(
    const ushort_t* __restrict__ Oh, const ushort_t* __restrict__ WT,
    const float* __restrict__ bout, float* __restrict__ outp)
{
  __shared__ ushort_t As[64 * 32];
  __shared__ ushort_t Bs[64 * 32];
  const int tid = threadIdx.x;
  const int lane = tid & 63, w = tid >> 6;
  const int wr = w >> 1, wc = w & 1;          // wave tile 32x32
  const int quad = lane >> 4, l16 = lane & 15;
  const int m0 = blockIdx.y * 64, n0 = blockIdx.x * 64;

  f32x4 acc[2][2];
#pragma unroll
  for (int i = 0; i < 2; i++)
#pragma unroll
    for (int j = 0; j < 2; j++) acc[i][j] = f32x4{0.f, 0.f, 0.f, 0.f};

  const int idx = tid * 8;
  const int ra = idx >> 5, ca = idx & 31;

  for (int k0 = 0; k0 < 512; k0 += 32) {
    s16x8 va = *(const s16x8*)(Oh + (m0 + ra) * 512 + k0 + ca);
    s16x8 vb = *(const s16x8*)(WT + (n0 + ra) * 512 + k0 + ca);
    __syncthreads();
    *(s16x8*)(As + idx) = va;
    *(s16x8*)(Bs + idx) = vb;
    __syncthreads();

    s16x8 af[2], bfr[2];
#pragma unroll
    for (int mt = 0; mt < 2; mt++)
      af[mt] = *(const s16x8*)(As + (wr * 32 + mt * 16 + l16) * 32 + quad * 8);
#pragma unroll
    for (int nt = 0; nt < 2; nt++)
      bfr[nt] = *(const s16x8*)(Bs + (wc * 32 + nt * 16 + l16) * 32 + quad * 8);
#pragma unroll
    for (int mt = 0; mt < 2; mt++)
#pragma unroll
      for (int nt = 0; nt < 2; nt++)
        acc[mt][nt] = __builtin_amdgcn_mfma_f32_16x16x32_bf16(af[mt], bfr[nt], acc[mt][nt], 0, 0, 0);
  }

#pragma unroll
  for (int nt = 0; nt < 2; nt++) {
    int c = n0 + wc * 32 + nt * 16 + l16;
    float bias = bout[c];
#pragma unroll
    for (int mt = 0; mt < 2; mt++) {
#pragma unroll
      for (int rr = 0; rr < 4; rr++) {
        int m = m0 + wr * 32 + mt * 16 + quad * 4 + rr;
        outp[m * 512 + c] = acc[mt][nt][rr] + bias;
      }
    }
  }
}

extern "C" void kernel_launch(void* const* d_in, const int* in_sizes, int n_in,
                              void* d_out, int out_size, void* d_ws, size_t ws_size,
                              hipStream_t stream)
{
  const float* x    = (const float*)d_in[0];
  const float* Wqkv = (const float*)d_in[1];
  const float* bqkv = (const float*)d_in[2];
  const float* Wod  = (const float*)d_in[3];
  const float* bod  = (const float*)d_in[4];
  const float* Wout = (const float*)d_in[5];
  const float* bout = (const float*)d_in[6];
  const int* lenp   = (const int*)d_in[7];

  char* ws = (char*)d_ws;
  ushort_t* WqkvT  = (ushort_t*)(ws);                  // 1536x512 bf16
  ushort_t* WoT    = (ushort_t*)(ws + 1572864);        // 512x512 bf16
  ushort_t* xb     = (ushort_t*)(ws + 2097152);        // 2048x512 bf16
  ushort_t* Qh     = (ushort_t*)(ws + 4194304);        // 16x1024x64 bf16 (pre-scaled 0.125)
  ushort_t* Kh     = (ushort_t*)(ws + 6291456);        // 16x1024x64 bf16
  ushort_t* VT     = (ushort_t*)(ws + 8388608);        // 16x64x1024 bf16
  ushort_t* VhOh   = (ushort_t*)(ws + 10485760);       // Vh, then (after v_transpose) Oh
  float*    Wcomb  = (float*)(ws + 12582912);          // 512x16 f32
  float*    bcomb  = (float*)(ws + 12615680);          // 16 f32
  float*    params = (float*)(ws + 12615744);          // 16x1024x6 f32

  transpose_conv_kernel<<<dim3(24, 8), 256, 0, stream>>>(Wqkv, WqkvT, 512, 1536);
  transpose_conv_kernel<<<dim3(8, 8), 256, 0, stream>>>(Wout, WoT, 512, 512);
  fold_kernel<<<513, 64, 0, stream>>>(Wqkv, bqkv, Wod, bod, Wcomb, bcomb);
  od_kernel<<<512, 256, 0, stream>>>(x, Wcomb, bcomb, lenp, params, xb);
  qkv_gemm_kernel<<<dim3(12, 32), 256, 0, stream>>>(xb, WqkvT, bqkv, Qh, Kh, VhOh);
  v_transpose_kernel<<<dim3(16, 16), 256, 0, stream>>>(VhOh, VT);
  // after v_transpose, the Vh slot is dead -> attn reuses it as Oh (stream-ordered)
  attn_kernel<<<dim3(16, 64), 512, 0, stream>>>(Qh, Kh, VT, params, VhOh);
  out_gemm_kernel<<<dim3(8, 32), 256, 0, stream>>>(VhOh, WoT, bout, (float*)d_out);
}

// Round 8
// 145.697 us; speedup vs baseline: 1.2735x; 1.2735x over previous
//
#include <hip/hip_runtime.h>

typedef unsigned short ushort_t;
typedef short s16x8 __attribute__((ext_vector_type(8)));   // bf16 frag vector
typedef float f32x4 __attribute__((ext_vector_type(4)));

#define DEVINL __device__ __forceinline__

DEVINL ushort_t f2b(float f) {           // fp32 -> bf16 RNE
  union { float f; unsigned int u; } v; v.f = f;
  unsigned int r = (v.u + 0x7fffu + ((v.u >> 16) & 1u)) >> 16;
  return (ushort_t)r;
}

// ---------- prep: fused {Wqkv transpose, Wout transpose, fold} ----------
// blocks [0,192): WqkvT[n*512+k] = Wqkv[k*1536+n]
// blocks [192,256): WoT[n*512+k] = Wout[k*512+n]
// blocks [256,385): fold rows c=(b-256)*4+wave: Wcomb[c][j]=sum_e' Wq[c][e']Wod[e'][j]
__global__ __launch_bounds__(256) void prep_kernel(
    const float* __restrict__ Wqkv, const float* __restrict__ bq,
    const float* __restrict__ Wod, const float* __restrict__ bod,
    const float* __restrict__ Wout,
    ushort_t* __restrict__ WqkvT, ushort_t* __restrict__ WoT,
    float* __restrict__ Wcomb, float* __restrict__ bcomb)
{
  __shared__ ushort_t tile[64 * 72];
  const int b = blockIdx.x;
  const int tid = threadIdx.x;

  if (b < 256) {
    const float* in;
    ushort_t* out;
    int N, bx, by;
    if (b < 192) { in = Wqkv; out = WqkvT; N = 1536; bx = b % 24; by = b / 24; }
    else         { in = Wout; out = WoT;   N = 512;  bx = (b - 192) % 8; by = (b - 192) / 8; }
    const int K = 512;
    const int n0 = bx * 64, k0 = by * 64;
    const int cr = tid >> 4;
    const int cc = (tid & 15) * 4;
#pragma unroll
    for (int p = 0; p < 4; p++) {
      int k = k0 + p * 16 + cr;
      float4 v = *(const float4*)(in + k * N + n0 + cc);
      ushort4 o; o.x = f2b(v.x); o.y = f2b(v.y); o.z = f2b(v.z); o.w = f2b(v.w);
      *(ushort4*)(tile + (p * 16 + cr) * 72 + cc) = o;
    }
    __syncthreads();
#pragma unroll
    for (int p = 0; p < 4; p++) {
      int n = n0 + p * 16 + cr;
      ushort4 v;
      v.x = tile[(cc + 0) * 72 + p * 16 + cr];
      v.y = tile[(cc + 1) * 72 + p * 16 + cr];
      v.z = tile[(cc + 2) * 72 + p * 16 + cr];
      v.w = tile[(cc + 3) * 72 + p * 16 + cr];
      *(ushort4*)(out + n * K + k0 + cc) = v;
    }
    return;
  }

  // fold: one wave per c-row
  const int w = tid >> 6, lane = tid & 63;
  const int c = (b - 256) * 4 + w;
  if (c > 512) return;
  float a[8];
  const float* src = (c < 512) ? (Wqkv + c * 1536 + lane * 8) : (bq + lane * 8);
  float4 a0 = *(const float4*)(src);
  float4 a1 = *(const float4*)(src + 4);
  a[0]=a0.x; a[1]=a0.y; a[2]=a0.z; a[3]=a0.w;
  a[4]=a1.x; a[5]=a1.y; a[6]=a1.z; a[7]=a1.w;

  float s[16];
#pragma unroll
  for (int j = 0; j < 16; j++) s[j] = 0.f;
#pragma unroll
  for (int i = 0; i < 8; i++) {
    const float* wp = Wod + (lane * 8 + i) * 16;
#pragma unroll
    for (int j = 0; j < 16; j++) s[j] += a[i] * wp[j];
  }
#pragma unroll
  for (int mask = 1; mask < 64; mask <<= 1)
#pragma unroll
    for (int j = 0; j < 16; j++) s[j] += __shfl_xor(s[j], mask);

  if (lane < 16) {
    if (c < 512) Wcomb[c * 16 + lane] = s[lane];
    else         bcomb[lane] = s[lane] + bod[lane];
  }
}

// ---------------- od (fp32) + x->bf16 conversion fused ----------------
__global__ __launch_bounds__(256) void od_kernel(
    const float* __restrict__ x, const float* __restrict__ Wcomb,
    const float* __restrict__ bcomb, const int* __restrict__ lenp,
    float* __restrict__ params, ushort_t* __restrict__ xb)
{
  const int w = threadIdx.x >> 6, lane = threadIdx.x & 63;
  const int m = blockIdx.x * 4 + w;   // 0..2047
  int li = lenp[0];
  float len = (li > 0 && li < 1048576) ? (float)li : 1024.0f;

  const float* qp = x + m * 512 + lane * 8;
  float q[8];
  float4 qa = *(const float4*)(qp);
  float4 qb = *(const float4*)(qp + 4);
  q[0]=qa.x; q[1]=qa.y; q[2]=qa.z; q[3]=qa.w;
  q[4]=qb.x; q[5]=qb.y; q[6]=qb.z; q[7]=qb.w;

  s16x8 ov;
#pragma unroll
  for (int i = 0; i < 8; i++) ov[i] = (short)f2b(q[i]);
  *(s16x8*)(xb + m * 512 + lane * 8) = ov;

  float s[16];
#pragma unroll
  for (int j = 0; j < 16; j++) s[j] = 0.f;
#pragma unroll
  for (int i = 0; i < 8; i++) {
    const float* wp = Wcomb + (lane * 8 + i) * 16;
#pragma unroll
    for (int j = 0; j < 16; j++) s[j] += q[i] * wp[j];
  }
#pragma unroll
  for (int mask = 1; mask < 64; mask <<= 1)
#pragma unroll
    for (int j = 0; j < 16; j++) s[j] += __shfl_xor(s[j], mask);

  if (lane < 8) {
    int h = lane;
    int bb = m >> 10, t = m & 1023;
    float odo = s[h] + bcomb[h];
    float odd = s[8 + h] + bcomb[8 + h];
    float offset = tanhf(odo) * len;
    float dur = len / (1.f + expf(-odd));
    float anchor = (float)t + offset;
    float start = anchor - dur, end = anchor + dur;
    float bl = floorf(start), br = ceilf(end);
    float al = floorf(anchor);
    float da = anchor - al;
    float* pp = params + ((bb * 8 + h) * 1024 + t) * 6;
    pp[0] = bl; pp[1] = br; pp[2] = al;
    pp[3] = bl - start; pp[4] = end - br; pp[5] = da;
  }
}

// ------- qkv GEMM: 64x128 tiles, grid (12,32); Q pre-scaled 0.125; VT direct -------
__global__ __launch_bounds__(256) void qkv_gemm_kernel(
    const ushort_t* __restrict__ xb, const ushort_t* __restrict__ WT,
    const float* __restrict__ bqkv,
    ushort_t* __restrict__ Qh, ushort_t* __restrict__ Kh, ushort_t* __restrict__ VT)
{
  __shared__ ushort_t As[64 * 32];
  __shared__ ushort_t Bs[128 * 32];
  const int tid = threadIdx.x;
  const int lane = tid & 63, w = tid >> 6;
  const int wr = w >> 1, wc = w & 1;          // wave tile 32x64
  const int quad = lane >> 4, l16 = lane & 15;
  const int m0 = blockIdx.y * 64, n0 = blockIdx.x * 128;

  f32x4 acc[2][4];
#pragma unroll
  for (int i = 0; i < 2; i++)
#pragma unroll
    for (int j = 0; j < 4; j++) acc[i][j] = f32x4{0.f, 0.f, 0.f, 0.f};

  const int idx = tid * 8;
  const int ra = idx >> 5, ca = idx & 31;
  const int rb1 = (idx + 2048) >> 5, cb1 = (idx + 2048) & 31;

  for (int k0 = 0; k0 < 512; k0 += 32) {
    s16x8 va  = *(const s16x8*)(xb + (m0 + ra) * 512 + k0 + ca);
    s16x8 vb0 = *(const s16x8*)(WT + (n0 + ra) * 512 + k0 + ca);
    s16x8 vb1 = *(const s16x8*)(WT + (n0 + rb1) * 512 + k0 + cb1);
    __syncthreads();
    *(s16x8*)(As + idx) = va;
    *(s16x8*)(Bs + idx) = vb0;
    *(s16x8*)(Bs + idx + 2048) = vb1;
    __syncthreads();

    s16x8 af[2], bfr[4];
#pragma unroll
    for (int mt = 0; mt < 2; mt++)
      af[mt] = *(const s16x8*)(As + (wr * 32 + mt * 16 + l16) * 32 + quad * 8);
#pragma unroll
    for (int nt = 0; nt < 4; nt++)
      bfr[nt] = *(const s16x8*)(Bs + (wc * 64 + nt * 16 + l16) * 32 + quad * 8);
#pragma unroll
    for (int mt = 0; mt < 2; mt++)
#pragma unroll
      for (int nt = 0; nt < 4; nt++)
        acc[mt][nt] = __builtin_amdgcn_mfma_f32_16x16x32_bf16(af[mt], bfr[nt], acc[mt][nt], 0, 0, 0);
  }

#pragma unroll
  for (int nt = 0; nt < 4; nt++) {
    int c = n0 + wc * 64 + nt * 16 + l16;
    float bias = bqkv[c];
    int which = c >> 9;
    int e = c & 511;
    int h = e >> 6, d = e & 63;
#pragma unroll
    for (int mt = 0; mt < 2; mt++) {
      int mbase = m0 + wr * 32 + mt * 16 + quad * 4;
      int bb = mbase >> 10, t = mbase & 1023;
      int bh = bb * 8 + h;
      if (which == 2) {
        // VT[bh][d][t..t+3]: 4 consecutive t -> one 8B store
        ushort4 pk;
        pk.x = f2b(acc[mt][nt][0] + bias);
        pk.y = f2b(acc[mt][nt][1] + bias);
        pk.z = f2b(acc[mt][nt][2] + bias);
        pk.w = f2b(acc[mt][nt][3] + bias);
        *(ushort4*)(VT + (bh * 64 + d) * 1024 + t) = pk;
      } else {
        ushort_t* dst = (which == 0) ? Qh : Kh;
        float sc = (which == 0) ? 0.125f : 1.0f;
#pragma unroll
        for (int rr = 0; rr < 4; rr++)
          dst[(bh * 1024 + t + rr) * 64 + d] = f2b((acc[mt][nt][rr] + bias) * sc);
      }
    }
  }
}

// ------- attention: no-max softmax, split-4, K+V preload, no fence -------
// grid (bh, qtile): all blocks of a head land on one XCD (i%8 heuristic).
__global__ __launch_bounds__(256) void attn_kernel(
    const ushort_t* __restrict__ Qh, const ushort_t* __restrict__ Kh,
    const ushort_t* __restrict__ VT, const float* __restrict__ params,
    ushort_t* __restrict__ Oh)
{
  __shared__ ushort_t Plds[4 * 16 * 72];
  __shared__ float Om[4][16][65];
  __shared__ float lwS[4][16];

  const int tid = threadIdx.x;
  const int lane = tid & 63, w = tid >> 6;
  const int quad = lane >> 4, l16 = lane & 15;
  const int bh = blockIdx.x;
  const int mrow = blockIdx.y * 16;
  ushort_t* Pw = Plds + w * (16 * 72);

  s16x8 aq0 = *(const s16x8*)(Qh + (bh * 1024 + mrow + l16) * 64 + quad * 8);
  s16x8 aq1 = *(const s16x8*)(Qh + (bh * 1024 + mrow + l16) * 64 + 32 + quad * 8);

  float bl[4], br[4], al[4], wl[4], wr2[4], da[4];
  float lo = 1.0e9f, hi = -1.0e9f;
#pragma unroll
  for (int rr = 0; rr < 4; rr++) {
    int row = mrow + quad * 4 + rr;
    const float* pp = params + (bh * 1024 + row) * 6;
    bl[rr] = pp[0]; br[rr] = pp[1]; al[rr] = pp[2];
    wl[rr] = pp[3]; wr2[rr] = pp[4]; da[rr] = pp[5];
    bool empty = (br[rr] < 0.f) || (bl[rr] > 1023.f);
    float lo_r = empty ? 0.f    : fmaxf(bl[rr], 0.f);
    float hi_r = empty ? 1023.f : fminf(br[rr], 1023.f);
    lo = fminf(lo, lo_r); hi = fmaxf(hi, hi_r);
  }
  lo = fminf(lo, __shfl_xor(lo, 16));
  lo = fminf(lo, __shfl_xor(lo, 32));
  hi = fmaxf(hi, __shfl_xor(hi, 16));
  hi = fmaxf(hi, __shfl_xor(hi, 32));
  const int tlo = ((int)lo) >> 6, thi = ((int)hi) >> 6;

  float lr[4] = {0.f, 0.f, 0.f, 0.f};
  f32x4 Oacc[4];
#pragma unroll
  for (int nt = 0; nt < 4; nt++) Oacc[nt] = f32x4{0.f, 0.f, 0.f, 0.f};

  for (int tt = tlo + w; tt <= thi; tt += 4) {
    const int r0 = tt * 64;

    // K and V fragments both issued up front; V is independent of the S chain,
    // so it stays in flight (vmcnt) while QK-MFMA + softmax run.
    s16x8 bk0[4], bk1[4], bv0[4], bv1[4];
#pragma unroll
    for (int nt = 0; nt < 4; nt++) {
      const ushort_t* kp = Kh + (bh * 1024 + r0 + nt * 16 + l16) * 64 + quad * 8;
      bk0[nt] = *(const s16x8*)(kp);
      bk1[nt] = *(const s16x8*)(kp + 32);
    }
#pragma unroll
    for (int nt = 0; nt < 4; nt++) {
      const ushort_t* vp = VT + (bh * 64 + nt * 16 + l16) * 1024 + r0 + quad * 8;
      bv0[nt] = *(const s16x8*)(vp);
      bv1[nt] = *(const s16x8*)(vp + 32);
    }

    f32x4 S[4];
#pragma unroll
    for (int nt = 0; nt < 4; nt++) {
      f32x4 z = {0.f, 0.f, 0.f, 0.f};
      z = __builtin_amdgcn_mfma_f32_16x16x32_bf16(aq0, bk0[nt], z, 0, 0, 0);
      z = __builtin_amdgcn_mfma_f32_16x16x32_bf16(aq1, bk1[nt], z, 0, 0, 0);
      S[nt] = z;
    }

    // point-weight + mask + exp (no max subtraction: |s*wgt| <= ~12, fp32-safe;
    // mask=-30 => exp ~ 9e-14; all-masked row degrades to uniform softmax)
#pragma unroll
    for (int nt = 0; nt < 4; nt++) {
      float cf = (float)(r0 + nt * 16 + l16);
#pragma unroll
      for (int rr = 0; rr < 4; rr++) {
        float s = S[nt][rr];   // includes 0.125 via Qh pre-scale
        float wgt = 1.f;
        wgt += (cf == bl[rr]) ? wl[rr] : 0.f;
        wgt += (cf == br[rr]) ? wr2[rr] : 0.f;
        wgt += (cf == al[rr] + 1.f) ? da[rr] : 0.f;
        wgt += (cf == al[rr]) ? (1.f - da[rr]) : 0.f;
        s *= wgt;
        s = (cf < bl[rr] || cf > br[rr]) ? -30.f : s;
        float p = __expf(s);
        lr[rr] += p;
        S[nt][rr] = p;
      }
    }

    // P (C-layout) -> wave-private LDS -> A-operand layout.
    // Stores/loads are same TBAA family; compiler keeps order + inserts lgkmcnt.
#pragma unroll
    for (int nt = 0; nt < 4; nt++)
#pragma unroll
      for (int rr = 0; rr < 4; rr++)
        Pw[(quad * 4 + rr) * 72 + nt * 16 + l16] = f2b(S[nt][rr]);

    s16x8 pa0 = *(const s16x8*)(Pw + l16 * 72 + quad * 8);
    s16x8 pa1 = *(const s16x8*)(Pw + l16 * 72 + 32 + quad * 8);

#pragma unroll
    for (int nt = 0; nt < 4; nt++) {
      Oacc[nt] = __builtin_amdgcn_mfma_f32_16x16x32_bf16(pa0, bv0[nt], Oacc[nt], 0, 0, 0);
      Oacc[nt] = __builtin_amdgcn_mfma_f32_16x16x32_bf16(pa1, bv1[nt], Oacc[nt], 0, 0, 0);
    }
  }

  // one row-sum reduction after the whole loop
#pragma unroll
  for (int mask = 1; mask < 16; mask <<= 1)
#pragma unroll
    for (int rr = 0; rr < 4; rr++) lr[rr] += __shfl_xor(lr[rr], mask);

#pragma unroll
  for (int nt = 0; nt < 4; nt++)
#pragma unroll
    for (int rr = 0; rr < 4; rr++)
      Om[w][quad * 4 + rr][nt * 16 + l16] = Oacc[nt][rr];
  if (l16 == 0) {
#pragma unroll
    for (int rr = 0; rr < 4; rr++) lwS[w][quad * 4 + rr] = lr[rr];
  }
  __syncthreads();

  // merge 4 partials (fixed m=0 -> plain sums)
  {
    const int col = tid & 63;
    const int rbase = (tid >> 6) * 4;
    const int bb = bh >> 3, h = bh & 7;
#pragma unroll
    for (int k = 0; k < 4; k++) {
      int r = rbase + k;
      float lg = lwS[0][r] + lwS[1][r] + lwS[2][r] + lwS[3][r];
      float o  = Om[0][r][col] + Om[1][r][col] + Om[2][r][col] + Om[3][r][col];
      int t = mrow + r;
      Oh[((bb << 10) + t) * 512 + h * 64 + col] = f2b(o / lg);
    }
  }
}

// ------- out GEMM: 64x64 tiles, grid (8,32)=256 blocks -------
__global__ __launch_bounds__(256) void out_gemm_kernel(
    const ushort_t* __restrict__ Oh, const ushort_t* __restrict__ WT,
    const float* __restrict__ bout, float* __restrict__ outp)
{
  __shared__ ushort_t As[64 * 32];
  __shared__ ushort_t Bs[64 * 32];
  const int tid = threadIdx.x;
  const int lane = tid & 63, w = tid >> 6;
  const int wr = w >> 1, wc = w & 1;          // wave tile 32x32
  const int quad = lane >> 4, l16 = lane & 15;
  const int m0 = blockIdx.y * 64, n0 = blockIdx.x * 64;

  f32x4 acc[2][2];
#pragma unroll
  for (int i = 0; i < 2; i++)
#pragma unroll
    for (int j = 0; j < 2; j++) acc[i][j] = f32x4{0.f, 0.f, 0.f, 0.f};

  const int idx = tid * 8;
  const int ra = idx >> 5, ca = idx & 31;

  for (int k0 = 0; k0 < 512; k0 += 32) {
    s16x8 va = *(const s16x8*)(Oh + (m0 + ra) * 512 + k0 + ca);
    s16x8 vb = *(const s16x8*)(WT + (n0 + ra) * 512 + k0 + ca);
    __syncthreads();
    *(s16x8*)(As + idx) = va;
    *(s16x8*)(Bs + idx) = vb;
    __syncthreads();

    s16x8 af[2], bfr[2];
#pragma unroll
    for (int mt = 0; mt < 2; mt++)
      af[mt] = *(const s16x8*)(As + (wr * 32 + mt * 16 + l16) * 32 + quad * 8);
#pragma unroll
    for (int nt = 0; nt < 2; nt++)
      bfr[nt] = *(const s16x8*)(Bs + (wc * 32 + nt * 16 + l16) * 32 + quad * 8);
#pragma unroll
    for (int mt = 0; mt < 2; mt++)
#pragma unroll
      for (int nt = 0; nt < 2; nt++)
        acc[mt][nt] = __builtin_amdgcn_mfma_f32_16x16x32_bf16(af[mt], bfr[nt], acc[mt][nt], 0, 0, 0);
  }

#pragma unroll
  for (int nt = 0; nt < 2; nt++) {
    int c = n0 + wc * 32 + nt * 16 + l16;
    float bias = bout[c];
#pragma unroll
    for (int mt = 0; mt < 2; mt++) {
#pragma unroll
      for (int rr = 0; rr < 4; rr++) {
        int m = m0 + wr * 32 + mt * 16 + quad * 4 + rr;
        outp[m * 512 + c] = acc[mt][nt][rr] + bias;
      }
    }
  }
}

extern "C" void kernel_launch(void* const* d_in, const int* in_sizes, int n_in,
                              void* d_out, int out_size, void* d_ws, size_t ws_size,
                              hipStream_t stream)
{
  const float* x    = (const float*)d_in[0];
  const float* Wqkv = (const float*)d_in[1];
  const float* bqkv = (const float*)d_in[2];
  const float* Wod  = (const float*)d_in[3];
  const float* bod  = (const float*)d_in[4];
  const float* Wout = (const float*)d_in[5];
  const float* bout = (const float*)d_in[6];
  const int* lenp   = (const int*)d_in[7];

  char* ws = (char*)d_ws;
  ushort_t* WqkvT  = (ushort_t*)(ws);                  // 1536x512 bf16
  ushort_t* WoT    = (ushort_t*)(ws + 1572864);        // 512x512 bf16
  ushort_t* xb     = (ushort_t*)(ws + 2097152);        // 2048x512 bf16
  ushort_t* Qh     = (ushort_t*)(ws + 4194304);        // 16x1024x64 bf16 (pre-scaled 0.125)
  ushort_t* Kh     = (ushort_t*)(ws + 6291456);        // 16x1024x64 bf16
  ushort_t* VT     = (ushort_t*)(ws + 8388608);        // 16x64x1024 bf16
  ushort_t* Oh     = (ushort_t*)(ws + 10485760);       // 2048x512 bf16
  float*    Wcomb  = (float*)(ws + 12582912);          // 512x16 f32
  float*    bcomb  = (float*)(ws + 12615680);          // 16 f32
  float*    params = (float*)(ws + 12615744);          // 16x1024x6 f32

  prep_kernel<<<385, 256, 0, stream>>>(Wqkv, bqkv, Wod, bod, Wout, WqkvT, WoT, Wcomb, bcomb);
  od_kernel<<<512, 256, 0, stream>>>(x, Wcomb, bcomb, lenp, params, xb);
  qkv_gemm_kernel<<<dim3(12, 32), 256, 0, stream>>>(xb, WqkvT, bqkv, Qh, Kh, VT);
  attn_kernel<<<dim3(16, 64), 256, 0, stream>>>(Qh, Kh, VT, params, Oh);
  out_gemm_kernel<<<dim3(8, 32), 256, 0, stream>>>(Oh, WoT, bout, (float*)d_out);
}

// Round 9
// 138.244 us; speedup vs baseline: 1.3421x; 1.0539x over previous
//
#include <hip/hip_runtime.h>

typedef unsigned short ushort_t;
typedef short s16x8 __attribute__((ext_vector_type(8)));   // bf16 frag vector
typedef float f32x4 __attribute__((ext_vector_type(4)));

#define DEVINL __device__ __forceinline__

DEVINL ushort_t f2b(float f) {           // fp32 -> bf16 RNE
  union { float f; unsigned int u; } v; v.f = f;
  unsigned int r = (v.u + 0x7fffu + ((v.u >> 16) & 1u)) >> 16;
  return (ushort_t)r;
}

// ---------- prep: fused {Wqkv transpose, Wout transpose, fold} ----------
__global__ __launch_bounds__(256) void prep_kernel(
    const float* __restrict__ Wqkv, const float* __restrict__ bq,
    const float* __restrict__ Wod, const float* __restrict__ bod,
    const float* __restrict__ Wout,
    ushort_t* __restrict__ WqkvT, ushort_t* __restrict__ WoT,
    float* __restrict__ Wcomb, float* __restrict__ bcomb)
{
  __shared__ ushort_t tile[64 * 72];
  const int b = blockIdx.x;
  const int tid = threadIdx.x;

  if (b < 256) {
    const float* in;
    ushort_t* out;
    int N, bx, by;
    if (b < 192) { in = Wqkv; out = WqkvT; N = 1536; bx = b % 24; by = b / 24; }
    else         { in = Wout; out = WoT;   N = 512;  bx = (b - 192) % 8; by = (b - 192) / 8; }
    const int K = 512;
    const int n0 = bx * 64, k0 = by * 64;
    const int cr = tid >> 4;
    const int cc = (tid & 15) * 4;
#pragma unroll
    for (int p = 0; p < 4; p++) {
      int k = k0 + p * 16 + cr;
      float4 v = *(const float4*)(in + k * N + n0 + cc);
      ushort4 o; o.x = f2b(v.x); o.y = f2b(v.y); o.z = f2b(v.z); o.w = f2b(v.w);
      *(ushort4*)(tile + (p * 16 + cr) * 72 + cc) = o;
    }
    __syncthreads();
#pragma unroll
    for (int p = 0; p < 4; p++) {
      int n = n0 + p * 16 + cr;
      ushort4 v;
      v.x = tile[(cc + 0) * 72 + p * 16 + cr];
      v.y = tile[(cc + 1) * 72 + p * 16 + cr];
      v.z = tile[(cc + 2) * 72 + p * 16 + cr];
      v.w = tile[(cc + 3) * 72 + p * 16 + cr];
      *(ushort4*)(out + n * K + k0 + cc) = v;
    }
    return;
  }

  // fold: one wave per c-row
  const int w = tid >> 6, lane = tid & 63;
  const int c = (b - 256) * 4 + w;
  if (c > 512) return;
  float a[8];
  const float* src = (c < 512) ? (Wqkv + c * 1536 + lane * 8) : (bq + lane * 8);
  float4 a0 = *(const float4*)(src);
  float4 a1 = *(const float4*)(src + 4);
  a[0]=a0.x; a[1]=a0.y; a[2]=a0.z; a[3]=a0.w;
  a[4]=a1.x; a[5]=a1.y; a[6]=a1.z; a[7]=a1.w;

  float s[16];
#pragma unroll
  for (int j = 0; j < 16; j++) s[j] = 0.f;
#pragma unroll
  for (int i = 0; i < 8; i++) {
    const float* wp = Wod + (lane * 8 + i) * 16;
#pragma unroll
    for (int j = 0; j < 16; j++) s[j] += a[i] * wp[j];
  }
#pragma unroll
  for (int mask = 1; mask < 64; mask <<= 1)
#pragma unroll
    for (int j = 0; j < 16; j++) s[j] += __shfl_xor(s[j], mask);

  if (lane < 16) {
    if (c < 512) Wcomb[c * 16 + lane] = s[lane];
    else         bcomb[lane] = s[lane] + bod[lane];
  }
}

// ---------------- od (fp32) + x->bf16 conversion fused ----------------
__global__ __launch_bounds__(256) void od_kernel(
    const float* __restrict__ x, const float* __restrict__ Wcomb,
    const float* __restrict__ bcomb, const int* __restrict__ lenp,
    float* __restrict__ params, ushort_t* __restrict__ xb)
{
  const int w = threadIdx.x >> 6, lane = threadIdx.x & 63;
  const int m = blockIdx.x * 4 + w;   // 0..2047
  int li = lenp[0];
  float len = (li > 0 && li < 1048576) ? (float)li : 1024.0f;

  const float* qp = x + m * 512 + lane * 8;
  float q[8];
  float4 qa = *(const float4*)(qp);
  float4 qb = *(const float4*)(qp + 4);
  q[0]=qa.x; q[1]=qa.y; q[2]=qa.z; q[3]=qa.w;
  q[4]=qb.x; q[5]=qb.y; q[6]=qb.z; q[7]=qb.w;

  s16x8 ov;
#pragma unroll
  for (int i = 0; i < 8; i++) ov[i] = (short)f2b(q[i]);
  *(s16x8*)(xb + m * 512 + lane * 8) = ov;

  float s[16];
#pragma unroll
  for (int j = 0; j < 16; j++) s[j] = 0.f;
#pragma unroll
  for (int i = 0; i < 8; i++) {
    const float* wp = Wcomb + (lane * 8 + i) * 16;
#pragma unroll
    for (int j = 0; j < 16; j++) s[j] += q[i] * wp[j];
  }
#pragma unroll
  for (int mask = 1; mask < 64; mask <<= 1)
#pragma unroll
    for (int j = 0; j < 16; j++) s[j] += __shfl_xor(s[j], mask);

  if (lane < 8) {
    int h = lane;
    int bb = m >> 10, t = m & 1023;
    float odo = s[h] + bcomb[h];
    float odd = s[8 + h] + bcomb[8 + h];
    float offset = tanhf(odo) * len;
    float dur = len / (1.f + expf(-odd));
    float anchor = (float)t + offset;
    float start = anchor - dur, end = anchor + dur;
    float bl = floorf(start), br = ceilf(end);
    float al = floorf(anchor);
    float da = anchor - al;
    float* pp = params + ((bb * 8 + h) * 1024 + t) * 6;
    pp[0] = bl; pp[1] = br; pp[2] = al;
    pp[3] = bl - start; pp[4] = end - br; pp[5] = da;
  }
}

// ------- qkv GEMM: 64x128 tiles, grid (12,32); Q pre-scaled 0.125; VT direct -------
__global__ __launch_bounds__(256) void qkv_gemm_kernel(
    const ushort_t* __restrict__ xb, const ushort_t* __restrict__ WT,
    const float* __restrict__ bqkv,
    ushort_t* __restrict__ Qh, ushort_t* __restrict__ Kh, ushort_t* __restrict__ VT)
{
  __shared__ ushort_t As[64 * 32];
  __shared__ ushort_t Bs[128 * 32];
  const int tid = threadIdx.x;
  const int lane = tid & 63, w = tid >> 6;
  const int wr = w >> 1, wc = w & 1;          // wave tile 32x64
  const int quad = lane >> 4, l16 = lane & 15;
  const int m0 = blockIdx.y * 64, n0 = blockIdx.x * 128;

  f32x4 acc[2][4];
#pragma unroll
  for (int i = 0; i < 2; i++)
#pragma unroll
    for (int j = 0; j < 4; j++) acc[i][j] = f32x4{0.f, 0.f, 0.f, 0.f};

  const int idx = tid * 8;
  const int ra = idx >> 5, ca = idx & 31;
  const int rb1 = (idx + 2048) >> 5, cb1 = (idx + 2048) & 31;

  for (int k0 = 0; k0 < 512; k0 += 32) {
    s16x8 va  = *(const s16x8*)(xb + (m0 + ra) * 512 + k0 + ca);
    s16x8 vb0 = *(const s16x8*)(WT + (n0 + ra) * 512 + k0 + ca);
    s16x8 vb1 = *(const s16x8*)(WT + (n0 + rb1) * 512 + k0 + cb1);
    __syncthreads();
    *(s16x8*)(As + idx) = va;
    *(s16x8*)(Bs + idx) = vb0;
    *(s16x8*)(Bs + idx + 2048) = vb1;
    __syncthreads();

    s16x8 af[2], bfr[4];
#pragma unroll
    for (int mt = 0; mt < 2; mt++)
      af[mt] = *(const s16x8*)(As + (wr * 32 + mt * 16 + l16) * 32 + quad * 8);
#pragma unroll
    for (int nt = 0; nt < 4; nt++)
      bfr[nt] = *(const s16x8*)(Bs + (wc * 64 + nt * 16 + l16) * 32 + quad * 8);
#pragma unroll
    for (int mt = 0; mt < 2; mt++)
#pragma unroll
      for (int nt = 0; nt < 4; nt++)
        acc[mt][nt] = __builtin_amdgcn_mfma_f32_16x16x32_bf16(af[mt], bfr[nt], acc[mt][nt], 0, 0, 0);
  }

#pragma unroll
  for (int nt = 0; nt < 4; nt++) {
    int c = n0 + wc * 64 + nt * 16 + l16;
    float bias = bqkv[c];
    int which = c >> 9;
    int e = c & 511;
    int h = e >> 6, d = e & 63;
#pragma unroll
    for (int mt = 0; mt < 2; mt++) {
      int mbase = m0 + wr * 32 + mt * 16 + quad * 4;
      int bb = mbase >> 10, t = mbase & 1023;
      int bh = bb * 8 + h;
      if (which == 2) {
        ushort4 pk;
        pk.x = f2b(acc[mt][nt][0] + bias);
        pk.y = f2b(acc[mt][nt][1] + bias);
        pk.z = f2b(acc[mt][nt][2] + bias);
        pk.w = f2b(acc[mt][nt][3] + bias);
        *(ushort4*)(VT + (bh * 64 + d) * 1024 + t) = pk;
      } else {
        ushort_t* dst = (which == 0) ? Qh : Kh;
        float sc = (which == 0) ? 0.125f : 1.0f;
#pragma unroll
        for (int rr = 0; rr < 4; rr++)
          dst[(bh * 1024 + t + rr) * 64 + d] = f2b((acc[mt][nt][rr] + bias) * sc);
      }
    }
  }
}

// ------- attention: no-max softmax, split-4, K+V preload -------
// __launch_bounds__(256, 2): cap occupancy target at 2 waves/EU so the
// allocator gives ~256 VGPRs -> the 16 preloaded K/V fragments actually
// stay resident and all global loads issue up front (MLP). At the default
// bound the kernel compiled to 80 VGPRs and the compiler serialized the
// loads -> ~10k-cycle per-tile chains (round-3..8 plateau).
__global__ __launch_bounds__(256, 2) void attn_kernel(
    const ushort_t* __restrict__ Qh, const ushort_t* __restrict__ Kh,
    const ushort_t* __restrict__ VT, const float* __restrict__ params,
    ushort_t* __restrict__ Oh)
{
  __shared__ ushort_t Plds[4 * 16 * 72];
  __shared__ float Om[4][16][65];
  __shared__ float lwS[4][16];

  const int tid = threadIdx.x;
  const int lane = tid & 63, w = tid >> 6;
  const int quad = lane >> 4, l16 = lane & 15;
  const int bh = blockIdx.x;
  const int mrow = blockIdx.y * 16;
  ushort_t* Pw = Plds + w * (16 * 72);

  s16x8 aq0 = *(const s16x8*)(Qh + (bh * 1024 + mrow + l16) * 64 + quad * 8);
  s16x8 aq1 = *(const s16x8*)(Qh + (bh * 1024 + mrow + l16) * 64 + 32 + quad * 8);

  float bl[4], br[4], al[4], wl[4], wr2[4], da[4];
  float lo = 1.0e9f, hi = -1.0e9f;
#pragma unroll
  for (int rr = 0; rr < 4; rr++) {
    int row = mrow + quad * 4 + rr;
    const float* pp = params + (bh * 1024 + row) * 6;
    bl[rr] = pp[0]; br[rr] = pp[1]; al[rr] = pp[2];
    wl[rr] = pp[3]; wr2[rr] = pp[4]; da[rr] = pp[5];
    bool empty = (br[rr] < 0.f) || (bl[rr] > 1023.f);
    float lo_r = empty ? 0.f    : fmaxf(bl[rr], 0.f);
    float hi_r = empty ? 1023.f : fminf(br[rr], 1023.f);
    lo = fminf(lo, lo_r); hi = fmaxf(hi, hi_r);
  }
  lo = fminf(lo, __shfl_xor(lo, 16));
  lo = fminf(lo, __shfl_xor(lo, 32));
  hi = fmaxf(hi, __shfl_xor(hi, 16));
  hi = fmaxf(hi, __shfl_xor(hi, 32));
  const int tlo = ((int)lo) >> 6, thi = ((int)hi) >> 6;

  float lr[4] = {0.f, 0.f, 0.f, 0.f};
  f32x4 Oacc[4];
#pragma unroll
  for (int nt = 0; nt < 4; nt++) Oacc[nt] = f32x4{0.f, 0.f, 0.f, 0.f};

  for (int tt = tlo + w; tt <= thi; tt += 4) {
    const int r0 = tt * 64;

    // All 16 K/V fragment loads issued up front; with the 256-VGPR budget
    // they stay in flight (vmcnt) while the S chain runs.
    s16x8 bk0[4], bk1[4], bv0[4], bv1[4];
#pragma unroll
    for (int nt = 0; nt < 4; nt++) {
      const ushort_t* kp = Kh + (bh * 1024 + r0 + nt * 16 + l16) * 64 + quad * 8;
      bk0[nt] = *(const s16x8*)(kp);
      bk1[nt] = *(const s16x8*)(kp + 32);
    }
#pragma unroll
    for (int nt = 0; nt < 4; nt++) {
      const ushort_t* vp = VT + (bh * 64 + nt * 16 + l16) * 1024 + r0 + quad * 8;
      bv0[nt] = *(const s16x8*)(vp);
      bv1[nt] = *(const s16x8*)(vp + 32);
    }

    f32x4 S[4];
#pragma unroll
    for (int nt = 0; nt < 4; nt++) {
      f32x4 z = {0.f, 0.f, 0.f, 0.f};
      z = __builtin_amdgcn_mfma_f32_16x16x32_bf16(aq0, bk0[nt], z, 0, 0, 0);
      z = __builtin_amdgcn_mfma_f32_16x16x32_bf16(aq1, bk1[nt], z, 0, 0, 0);
      S[nt] = z;
    }

    // point-weight + mask + exp (no max subtraction: |s*wgt| <= ~12, fp32-safe;
    // mask=-30 => exp ~ 9e-14; all-masked row degrades to uniform softmax)
#pragma unroll
    for (int nt = 0; nt < 4; nt++) {
      float cf = (float)(r0 + nt * 16 + l16);
#pragma unroll
      for (int rr = 0; rr < 4; rr++) {
        float s = S[nt][rr];   // includes 0.125 via Qh pre-scale
        float wgt = 1.f;
        wgt += (cf == bl[rr]) ? wl[rr] : 0.f;
        wgt += (cf == br[rr]) ? wr2[rr] : 0.f;
        wgt += (cf == al[rr] + 1.f) ? da[rr] : 0.f;
        wgt += (cf == al[rr]) ? (1.f - da[rr]) : 0.f;
        s *= wgt;
        s = (cf < bl[rr] || cf > br[rr]) ? -30.f : s;
        float p = __expf(s);
        lr[rr] += p;
        S[nt][rr] = p;
      }
    }

    // P (C-layout) -> wave-private LDS -> A-operand layout.
#pragma unroll
    for (int nt = 0; nt < 4; nt++)
#pragma unroll
      for (int rr = 0; rr < 4; rr++)
        Pw[(quad * 4 + rr) * 72 + nt * 16 + l16] = f2b(S[nt][rr]);

    s16x8 pa0 = *(const s16x8*)(Pw + l16 * 72 + quad * 8);
    s16x8 pa1 = *(const s16x8*)(Pw + l16 * 72 + 32 + quad * 8);

#pragma unroll
    for (int nt = 0; nt < 4; nt++) {
      Oacc[nt] = __builtin_amdgcn_mfma_f32_16x16x32_bf16(pa0, bv0[nt], Oacc[nt], 0, 0, 0);
      Oacc[nt] = __builtin_amdgcn_mfma_f32_16x16x32_bf16(pa1, bv1[nt], Oacc[nt], 0, 0, 0);
    }
  }

  // one row-sum reduction after the whole loop
#pragma unroll
  for (int mask = 1; mask < 16; mask <<= 1)
#pragma unroll
    for (int rr = 0; rr < 4; rr++) lr[rr] += __shfl_xor(lr[rr], mask);

#pragma unroll
  for (int nt = 0; nt < 4; nt++)
#pragma unroll
    for (int rr = 0; rr < 4; rr++)
      Om[w][quad * 4 + rr][nt * 16 + l16] = Oacc[nt][rr];
  if (l16 == 0) {
#pragma unroll
    for (int rr = 0; rr < 4; rr++) lwS[w][quad * 4 + rr] = lr[rr];
  }
  __syncthreads();

  // merge 4 partials (fixed m=0 -> plain sums)
  {
    const int col = tid & 63;
    const int rbase = (tid >> 6) * 4;
    const int bb = bh >> 3, h = bh & 7;
#pragma unroll
    for (int k = 0; k < 4; k++) {
      int r = rbase + k;
      float lg = lwS[0][r] + lwS[1][r] + lwS[2][r] + lwS[3][r];
      float o  = Om[0][r][col] + Om[1][r][col] + Om[2][r][col] + Om[3][r][col];
      int t = mrow + r;
      Oh[((bb << 10) + t) * 512 + h * 64 + col] = f2b(o / lg);
    }
  }
}

// ------- out GEMM: 64x64 tiles, grid (8,32)=256 blocks -------
__global__ __launch_bounds__(256) void out_gemm_kernel(
    const ushort_t* __restrict__ Oh, const ushort_t* __restrict__ WT,
    const float* __restrict__ bout, float* __restrict__ outp)
{
  __shared__ ushort_t As[64 * 32];
  __shared__ ushort_t Bs[64 * 32];
  const int tid = threadIdx.x;
  const int lane = tid & 63, w = tid >> 6;
  const int wr = w >> 1, wc = w & 1;          // wave tile 32x32
  const int quad = lane >> 4, l16 = lane & 15;
  const int m0 = blockIdx.y * 64, n0 = blockIdx.x * 64;

  f32x4 acc[2][2];
#pragma unroll
  for (int i = 0; i < 2; i++)
#pragma unroll
    for (int j = 0; j < 2; j++) acc[i][j] = f32x4{0.f, 0.f, 0.f, 0.f};

  const int idx = tid * 8;
  const int ra = idx >> 5, ca = idx & 31;

  for (int k0 = 0; k0 < 512; k0 += 32) {
    s16x8 va = *(const s16x8*)(Oh + (m0 + ra) * 512 + k0 + ca);
    s16x8 vb = *(const s16x8*)(WT + (n0 + ra) * 512 + k0 + ca);
    __syncthreads();
    *(s16x8*)(As + idx) = va;
    *(s16x8*)(Bs + idx) = vb;
    __syncthreads();

    s16x8 af[2], bfr[2];
#pragma unroll
    for (int mt = 0; mt < 2; mt++)
      af[mt] = *(const s16x8*)(As + (wr * 32 + mt * 16 + l16) * 32 + quad * 8);
#pragma unroll
    for (int nt = 0; nt < 2; nt++)
      bfr[nt] = *(const s16x8*)(Bs + (wc * 32 + nt * 16 + l16) * 32 + quad * 8);
#pragma unroll
    for (int mt = 0; mt < 2; mt++)
#pragma unroll
      for (int nt = 0; nt < 2; nt++)
        acc[mt][nt] = __builtin_amdgcn_mfma_f32_16x16x32_bf16(af[mt], bfr[nt], acc[mt][nt], 0, 0, 0);
  }

#pragma unroll
  for (int nt = 0; nt < 2; nt++) {
    int c = n0 + wc * 32 + nt * 16 + l16;
    float bias = bout[c];
#pragma unroll
    for (int mt = 0; mt < 2; mt++) {
#pragma unroll
      for (int rr = 0; rr < 4; rr++) {
        int m = m0 + wr * 32 + mt * 16 + quad * 4 + rr;
        outp[m * 512 + c] = acc[mt][nt][rr] + bias;
      }
    }
  }
}

extern "C" void kernel_launch(void* const* d_in, const int* in_sizes, int n_in,
                              void* d_out, int out_size, void* d_ws, size_t ws_size,
                              hipStream_t stream)
{
  const float* x    = (const float*)d_in[0];
  const float* Wqkv = (const float*)d_in[1];
  const float* bqkv = (const float*)d_in[2];
  const float* Wod  = (const float*)d_in[3];
  const float* bod  = (const float*)d_in[4];
  const float* Wout = (const float*)d_in[5];
  const float* bout = (const float*)d_in[6];
  const int* lenp   = (const int*)d_in[7];

  char* ws = (char*)d_ws;
  ushort_t* WqkvT  = (ushort_t*)(ws);                  // 1536x512 bf16
  ushort_t* WoT    = (ushort_t*)(ws + 1572864);        // 512x512 bf16
  ushort_t* xb     = (ushort_t*)(ws + 2097152);        // 2048x512 bf16
  ushort_t* Qh     = (ushort_t*)(ws + 4194304);        // 16x1024x64 bf16 (pre-scaled 0.125)
  ushort_t* Kh     = (ushort_t*)(ws + 6291456);        // 16x1024x64 bf16
  ushort_t* VT     = (ushort_t*)(ws + 8388608);        // 16x64x1024 bf16
  ushort_t* Oh     = (ushort_t*)(ws + 10485760);       // 2048x512 bf16
  float*    Wcomb  = (float*)(ws + 12582912);          // 512x16 f32
  float*    bcomb  = (float*)(ws + 12615680);          // 16 f32
  float*    params = (float*)(ws + 12615744);          // 16x1024x6 f32

  prep_kernel<<<385, 256, 0, stream>>>(Wqkv, bqkv, Wod, bod, Wout, WqkvT, WoT, Wcomb, bcomb);
  od_kernel<<<512, 256, 0, stream>>>(x, Wcomb, bcomb, lenp, params, xb);
  qkv_gemm_kernel<<<dim3(12, 32), 256, 0, stream>>>(xb, WqkvT, bqkv, Qh, Kh, VT);
  attn_kernel<<<dim3(16, 64), 256, 0, stream>>>(Qh, Kh, VT, params, Oh);
  out_gemm_kernel<<<dim3(8, 32), 256, 0, stream>>>(Oh, WoT, bout, (float*)d_out);
}